// Round 8
// baseline (245.481 us; speedup 1.0000x reference)
//
#include <hip/hip_runtime.h>

typedef __attribute__((ext_vector_type(8))) short bf16x8;
typedef __attribute__((ext_vector_type(4))) float f32x4;

#define CAPB 5632   // per-bucket capacity (mean E/NB ~= 4092, sd ~64)
#define NBMAX 512   // supports n <= 131072

static __device__ __forceinline__ unsigned short f2bf(float f) {
    unsigned u = __float_as_uint(f);
    unsigned r = (u + 0x7fff + ((u >> 16) & 1)) >> 16;  // RNE
    return (unsigned short)r;
}
static __device__ __forceinline__ float bfu_lo(unsigned v) { return __uint_as_float(v << 16); }
static __device__ __forceinline__ float bfu_hi(unsigned v) { return __uint_as_float(v & 0xffff0000u); }
static __device__ __forceinline__ unsigned packbf(float a, float b) {
    return (unsigned)f2bf(a) | ((unsigned)f2bf(b) << 16);
}

static __device__ __forceinline__ bf16x8 cvt8(float4 u0, float4 u1) {
    bf16x8 r;
    r[0] = (short)f2bf(u0.x); r[1] = (short)f2bf(u0.y);
    r[2] = (short)f2bf(u0.z); r[3] = (short)f2bf(u0.w);
    r[4] = (short)f2bf(u1.x); r[5] = (short)f2bf(u1.y);
    r[6] = (short)f2bf(u1.z); r[7] = (short)f2bf(u1.w);
    return r;
}

__global__ void k_zero_int(int* __restrict__ p, int n) {
    int i = blockIdx.x * blockDim.x + threadIdx.x;
    if (i < n) p[i] = 0;
}

// ---------------- Pass A: bucket edges by dst>>8, LDS-staged coalesced writes --------
__global__ __launch_bounds__(256) void k_passA(const int* __restrict__ row,
                                               const int* __restrict__ col,
                                               int* __restrict__ gcnt,
                                               unsigned long long* __restrict__ packed,
                                               int E, int NB) {
    __shared__ int lcnt[NBMAX];
    __shared__ int lbase[NBMAX];
    __shared__ int lcur[NBMAX];
    __shared__ int gbaseS[NBMAX];
    __shared__ unsigned long long stage[4096];
    __shared__ int s[256];

    int tid = threadIdx.x;
    int t0 = blockIdx.x * 4096;
    int total = min(4096, E - t0);

    for (int b = tid; b < NBMAX; b += 256) { lcnt[b] = 0; lcur[b] = 0; }
    __syncthreads();

    int er[16], ec[16];
#pragma unroll
    for (int j = 0; j < 16; ++j) {
        int e = t0 + j * 256 + tid;
        if (e < E) {
            er[j] = row[e];
            ec[j] = col[e];
            atomicAdd(&lcnt[ec[j] >> 8], 1);
        }
    }
    __syncthreads();

    int c0 = lcnt[2 * tid], c1 = lcnt[2 * tid + 1];
    int p = c0 + c1;
    s[tid] = p;
    __syncthreads();
    for (int off = 1; off < 256; off <<= 1) {
        int t = (tid >= off) ? s[tid - off] : 0;
        __syncthreads();
        s[tid] += t;
        __syncthreads();
    }
    int ebase = s[tid] - p;
    lbase[2 * tid] = ebase;
    lbase[2 * tid + 1] = ebase + c0;
    __syncthreads();

    for (int b = tid; b < NB; b += 256) {
        int lc = lcnt[b];
        if (lc > 0) gbaseS[b] = atomicAdd(&gcnt[b], lc);
    }
    __syncthreads();

#pragma unroll
    for (int j = 0; j < 16; ++j) {
        int e = t0 + j * 256 + tid;
        if (e < E) {
            int b = ec[j] >> 8;
            int pos = lbase[b] + atomicAdd(&lcur[b], 1);
            stage[pos] = ((unsigned long long)(unsigned)er[j] << 32) | (unsigned)ec[j];
        }
    }
    __syncthreads();

    for (int j = tid; j < total; j += 256) {
        unsigned long long v = stage[j];
        int b = ((int)(unsigned)v) >> 8;
        packed[(size_t)b * CAPB + gbaseS[b] + (j - lbase[b])] = v;
    }
}

__global__ void k_bscan(const int* __restrict__ gcnt, int* __restrict__ gbase,
                        int* __restrict__ indptr, int n, int E, int NB) {
    __shared__ int s[512];
    int tid = threadIdx.x;
    int v = (tid < NB) ? gcnt[tid] : 0;
    s[tid] = v;
    __syncthreads();
    for (int off = 1; off < 512; off <<= 1) {
        int t = (tid >= off) ? s[tid - off] : 0;
        __syncthreads();
        s[tid] += t;
        __syncthreads();
    }
    if (tid < NB) gbase[tid] = s[tid] - v;
    if (tid == 0) indptr[n] = E;
}

// ---------------- Pass B: per-bucket CSR finalize ----------------
__global__ __launch_bounds__(256) void k_passB(const unsigned long long* __restrict__ packed,
                                               const int* __restrict__ gcnt,
                                               const int* __restrict__ gbase,
                                               int* __restrict__ indptr,
                                               float* __restrict__ dinv,
                                               int* __restrict__ srcidx, int n) {
    __shared__ int ncnt[256];
    __shared__ int nbase[256];
    __shared__ int srow[CAPB];

    int b = blockIdx.x;
    int tid = threadIdx.x;
    int nodeBase = b << 8;
    int cntE = min(gcnt[b], CAPB);
    int base = gbase[b];
    size_t pb = (size_t)b * CAPB;

    ncnt[tid] = 0;
    __syncthreads();

    for (int j = tid; j < cntE; j += 256) {
        int c = (int)(unsigned)packed[pb + j];
        atomicAdd(&ncnt[c & 255], 1);
    }
    __syncthreads();

    int v = ncnt[tid];
    nbase[tid] = v;
    __syncthreads();
    for (int off = 1; off < 256; off <<= 1) {
        int t = (tid >= off) ? nbase[tid - off] : 0;
        __syncthreads();
        nbase[tid] += t;
        __syncthreads();
    }
    int excl = nbase[tid] - v;
    __syncthreads();
    nbase[tid] = excl;

    int node = nodeBase + tid;
    if (node < n) {
        indptr[node] = base + excl;
        dinv[node] = rsqrtf((float)(v + 1));
    }
    ncnt[tid] = 0;
    __syncthreads();

    for (int j = tid; j < cntE; j += 256) {
        unsigned long long e = packed[pb + j];
        int c = ((int)(unsigned)e) & 255;
        int r = (int)(e >> 32);
        int p = nbase[c] + atomicAdd(&ncnt[c], 1);
        srow[p] = r;
    }
    __syncthreads();

    for (int j = tid; j < cntE; j += 256) srcidx[base + j] = srow[j];
}

// ---------------- weight prep (both layers, one launch) ----------------
__global__ void k_wprep(const float* __restrict__ W1, const float* __restrict__ W2,
                        unsigned short* __restrict__ Wt1, unsigned short* __restrict__ Wt2) {
    int idx = blockIdx.x * blockDim.x + threadIdx.x;
    if (idx < 128 * 128) {
        int colc = idx >> 7, k = idx & 127;
        Wt1[colc * 128 + k] = f2bf(W1[k * 128 + colc]);
    } else if (idx < 128 * 128 + 64 * 128) {
        int j = idx - 128 * 128;
        int colc = j >> 7, k = j & 127;
        Wt2[colc * 128 + k] = f2bf(W2[k * 64 + colc]);
    }
}

// ---------------- gemm1 (fused concat+cast): Hs = dinv ⊙ (concat(x,cemb[cid]) @ W1t^T) ----
__global__ __launch_bounds__(256) void k_gemm1(const float* __restrict__ x,
                                               const int* __restrict__ cid,
                                               const float* __restrict__ cemb,
                                               const unsigned short* __restrict__ Wt,
                                               const float* __restrict__ dinv,
                                               unsigned short* __restrict__ D, int n) {
    int tid = threadIdx.x;
    int wid = tid >> 6, lane = tid & 63;
    int rbase = blockIdx.x * 64 + wid * 16;
    int lr = lane & 15, kq = lane >> 4;

    int arow = rbase + lr;
    if (arow > n - 1) arow = n - 1;
    const float* xp = x + (size_t)arow * 120 + kq * 8;

    bf16x8 a0 = cvt8(*(const float4*)(xp),      *(const float4*)(xp + 4));
    bf16x8 a1 = cvt8(*(const float4*)(xp + 32), *(const float4*)(xp + 36));
    bf16x8 a2 = cvt8(*(const float4*)(xp + 64), *(const float4*)(xp + 68));
    bf16x8 a3;
    if (kq < 3) {
        a3 = cvt8(*(const float4*)(xp + 96), *(const float4*)(xp + 100));
    } else {
        const float* cp = cemb + (size_t)cid[arow] * 8;
        a3 = cvt8(*(const float4*)(cp), *(const float4*)(cp + 4));
    }

    f32x4 acc[8];
#pragma unroll
    for (int cf = 0; cf < 8; ++cf) acc[cf] = (f32x4){0.f, 0.f, 0.f, 0.f};

#pragma unroll
    for (int cf = 0; cf < 8; ++cf) {
        const unsigned short* bp = Wt + (size_t)(cf * 16 + lr) * 128 + kq * 8;
        bf16x8 b0 = *(const bf16x8*)(bp);
        bf16x8 b1 = *(const bf16x8*)(bp + 32);
        bf16x8 b2 = *(const bf16x8*)(bp + 64);
        bf16x8 b3 = *(const bf16x8*)(bp + 96);
        acc[cf] = __builtin_amdgcn_mfma_f32_16x16x32_bf16(a0, b0, acc[cf], 0, 0, 0);
        acc[cf] = __builtin_amdgcn_mfma_f32_16x16x32_bf16(a1, b1, acc[cf], 0, 0, 0);
        acc[cf] = __builtin_amdgcn_mfma_f32_16x16x32_bf16(a2, b2, acc[cf], 0, 0, 0);
        acc[cf] = __builtin_amdgcn_mfma_f32_16x16x32_bf16(a3, b3, acc[cf], 0, 0, 0);
    }

    float dv[4];
#pragma unroll
    for (int r = 0; r < 4; ++r) {
        int grow = rbase + kq * 4 + r;
        dv[r] = (grow < n) ? dinv[grow] : 0.f;
    }
#pragma unroll
    for (int cf = 0; cf < 8; ++cf) {
#pragma unroll
        for (int r = 0; r < 4; ++r) {
            int grow = rbase + kq * 4 + r;
            if (grow < n) D[(size_t)grow * 128 + cf * 16 + lr] = f2bf(acc[cf][r] * dv[r]);
        }
    }
}

// ---------------- gemm2: Hs2 = dinv ⊙ (A[N,128] @ Wt^T) ----------------
template <int NOUT>
__global__ __launch_bounds__(256) void k_gemm_bf16(const unsigned short* __restrict__ A,
                                                   const unsigned short* __restrict__ Wt,
                                                   const float* __restrict__ dinv,
                                                   unsigned short* __restrict__ D, int n) {
    constexpr int NCF = NOUT / 16;
    int tid = threadIdx.x;
    int wid = tid >> 6, lane = tid & 63;
    int rbase = blockIdx.x * 64 + wid * 16;
    int lr = lane & 15, kq = lane >> 4;

    int arow = rbase + lr;
    if (arow > n - 1) arow = n - 1;
    const unsigned short* ap = A + (size_t)arow * 128 + kq * 8;
    bf16x8 a0 = *(const bf16x8*)(ap);
    bf16x8 a1 = *(const bf16x8*)(ap + 32);
    bf16x8 a2 = *(const bf16x8*)(ap + 64);
    bf16x8 a3 = *(const bf16x8*)(ap + 96);

    f32x4 acc[NCF];
#pragma unroll
    for (int cf = 0; cf < NCF; ++cf) acc[cf] = (f32x4){0.f, 0.f, 0.f, 0.f};

#pragma unroll
    for (int cf = 0; cf < NCF; ++cf) {
        const unsigned short* bp = Wt + (size_t)(cf * 16 + lr) * 128 + kq * 8;
        bf16x8 b0 = *(const bf16x8*)(bp);
        bf16x8 b1 = *(const bf16x8*)(bp + 32);
        bf16x8 b2 = *(const bf16x8*)(bp + 64);
        bf16x8 b3 = *(const bf16x8*)(bp + 96);
        acc[cf] = __builtin_amdgcn_mfma_f32_16x16x32_bf16(a0, b0, acc[cf], 0, 0, 0);
        acc[cf] = __builtin_amdgcn_mfma_f32_16x16x32_bf16(a1, b1, acc[cf], 0, 0, 0);
        acc[cf] = __builtin_amdgcn_mfma_f32_16x16x32_bf16(a2, b2, acc[cf], 0, 0, 0);
        acc[cf] = __builtin_amdgcn_mfma_f32_16x16x32_bf16(a3, b3, acc[cf], 0, 0, 0);
    }

    float dv[4];
#pragma unroll
    for (int r = 0; r < 4; ++r) {
        int grow = rbase + kq * 4 + r;
        dv[r] = (grow < n) ? dinv[grow] : 0.f;
    }
#pragma unroll
    for (int cf = 0; cf < NCF; ++cf) {
#pragma unroll
        for (int r = 0; r < 4; ++r) {
            int grow = rbase + kq * 4 + r;
            if (grow < n) D[(size_t)grow * NOUT + cf * 16 + lr] = f2bf(acc[cf][r] * dv[r]);
        }
    }
}

// ---------------- CSR aggregate (round-6 access pattern, 4 nodes/block, deep unroll) ----
// out[i,:] = dinv[i] * (sum_e Hs[src_e,:] + Hs[i,:]) + b[:]

// NC=128: 1 node/wave, 4 waves/block; lane = ushort2 (2 cols); unroll 8 -> 8 gathers in flight.
__global__ __launch_bounds__(256) void k_agg1(const unsigned* __restrict__ Hs,
                                              const int* __restrict__ indptr,
                                              const int* __restrict__ srcidx,
                                              const float* __restrict__ dinv,
                                              const float* __restrict__ bias,
                                              unsigned* __restrict__ Out, int n) {
    int wid = threadIdx.x >> 6, lane = threadIdx.x & 63;
    int i = blockIdx.x * 4 + wid;
    if (i >= n) return;
    float di = dinv[i];
    float2 b = *(const float2*)&bias[lane * 2];
    unsigned sv = Hs[(size_t)i * 64 + lane];
    float ax = bfu_lo(sv), ay = bfu_hi(sv);
    int e0 = indptr[i], e1 = indptr[i + 1];
#pragma unroll 8
    for (int e = e0; e < e1; ++e) {
        unsigned v = Hs[(size_t)srcidx[e] * 64 + lane];
        ax += bfu_lo(v);
        ay += bfu_hi(v);
    }
    float ox = fmaxf(di * ax + b.x, 0.f);
    float oy = fmaxf(di * ay + b.y, 0.f);
    Out[(size_t)i * 64 + lane] = packbf(ox, oy);
}

// NC=64: 1 node/wave, 4 waves/block; two 32-lane halves on even/odd edges; f32 out.
__global__ __launch_bounds__(256) void k_agg2(const unsigned* __restrict__ Hs,
                                              const int* __restrict__ indptr,
                                              const int* __restrict__ srcidx,
                                              const float* __restrict__ dinv,
                                              const float* __restrict__ bias,
                                              float2* __restrict__ Out, int n) {
    int wid = threadIdx.x >> 6, lane = threadIdx.x & 63;
    int i = blockIdx.x * 4 + wid;
    if (i >= n) return;
    int v = lane & 31, h = lane >> 5;
    float di = dinv[i];
    float2 b = *(const float2*)&bias[v * 2];
    float ax = 0.f, ay = 0.f;
    if (h == 0) {
        unsigned sv = Hs[(size_t)i * 32 + v];
        ax = bfu_lo(sv);
        ay = bfu_hi(sv);
    }
    int e0 = indptr[i], e1 = indptr[i + 1];
#pragma unroll 8
    for (int e = e0 + h; e < e1; e += 2) {
        unsigned w = Hs[(size_t)srcidx[e] * 32 + v];
        ax += bfu_lo(w);
        ay += bfu_hi(w);
    }
    ax += __shfl_xor(ax, 32);
    ay += __shfl_xor(ay, 32);
    if (h == 0) {
        Out[(size_t)i * 32 + v] = make_float2(di * ax + b.x, di * ay + b.y);
    }
}

// ---------------- launch ----------------

extern "C" void kernel_launch(void* const* d_in, const int* in_sizes, int n_in,
                              void* d_out, int out_size, void* d_ws, size_t ws_size,
                              hipStream_t stream) {
    const float* x    = (const float*)d_in[0];
    const int*   eidx = (const int*)d_in[1];
    const int*   cid  = (const int*)d_in[2];
    const float* cemb = (const float*)d_in[3];
    const float* W1   = (const float*)d_in[4];
    const float* b1   = (const float*)d_in[5];
    const float* W2   = (const float*)d_in[6];
    const float* b2   = (const float*)d_in[7];
    float* out = (float*)d_out;

    int n = in_sizes[2];
    int E = in_sizes[1] / 2;
    const int* row = eidx;
    const int* col = eidx + E;
    int NB = (n + 255) / 256;

    char* ws = (char*)d_ws;
    auto alloc = [&](size_t bytes) {
        char* p = ws;
        ws += (bytes + 255) & ~(size_t)255;
        return p;
    };
    float*              dinv   = (float*)alloc((size_t)n * 4);
    int*                gcnt   = (int*)alloc((size_t)NB * 4);
    int*                gbase  = (int*)alloc((size_t)NB * 4);
    int*                indptr = (int*)alloc((size_t)(n + 1) * 4);
    int*                srcidx = (int*)alloc((size_t)E * 4);
    unsigned long long* packed = (unsigned long long*)alloc((size_t)NB * CAPB * 8);
    unsigned short*     Wt1    = (unsigned short*)alloc(128 * 128 * 2);
    unsigned short*     Wt2    = (unsigned short*)alloc(64 * 128 * 2);
    unsigned short*     D1     = (unsigned short*)alloc((size_t)n * 128 * 2);
    unsigned short*     H1     = (unsigned short*)alloc((size_t)n * 128 * 2);
    unsigned short*     D2     = (unsigned short*)alloc((size_t)n * 64 * 2);

    // CSR build (bucketed two-pass)
    k_zero_int<<<(NB + 255) / 256, 256, 0, stream>>>(gcnt, NB);
    k_passA<<<(E + 4095) / 4096, 256, 0, stream>>>(row, col, gcnt, packed, E, NB);
    k_bscan<<<1, 512, 0, stream>>>(gcnt, gbase, indptr, n, E, NB);
    k_passB<<<NB, 256, 0, stream>>>(packed, gcnt, gbase, indptr, dinv, srcidx, n);

    // weight prep (single launch)
    k_wprep<<<(128 * 128 + 64 * 128 + 255) / 256, 256, 0, stream>>>(W1, W2, Wt1, Wt2);

    int gb = (n + 63) / 64;
    int ga = (n + 3) / 4;
    // layer 1
    k_gemm1<<<gb, 256, 0, stream>>>(x, cid, cemb, Wt1, dinv, D1, n);
    k_agg1<<<ga, 256, 0, stream>>>((const unsigned*)D1, indptr, srcidx, dinv, b1,
                                   (unsigned*)H1, n);
    // layer 2
    k_gemm_bf16<64><<<gb, 256, 0, stream>>>(H1, Wt2, dinv, D2, n);
    k_agg2<<<ga, 256, 0, stream>>>((const unsigned*)D2, indptr, srcidx, dinv, b2,
                                   (float2*)out, n);
}

// Round 9
// 213.246 us; speedup vs baseline: 1.1512x; 1.1512x over previous
//
#include <hip/hip_runtime.h>

typedef __attribute__((ext_vector_type(8))) short bf16x8;
typedef __attribute__((ext_vector_type(4))) float f32x4;

#define CAPB 5632   // per-bucket capacity (mean E/NB ~= 4092, sd ~64)
#define NBMAX 512   // supports n <= 131072

static __device__ __forceinline__ unsigned short f2bf(float f) {
    unsigned u = __float_as_uint(f);
    unsigned r = (u + 0x7fff + ((u >> 16) & 1)) >> 16;  // RNE
    return (unsigned short)r;
}
static __device__ __forceinline__ float bfu_lo(unsigned v) { return __uint_as_float(v << 16); }
static __device__ __forceinline__ float bfu_hi(unsigned v) { return __uint_as_float(v & 0xffff0000u); }
static __device__ __forceinline__ unsigned packbf(float a, float b) {
    return (unsigned)f2bf(a) | ((unsigned)f2bf(b) << 16);
}

static __device__ __forceinline__ bf16x8 cvt8(float4 u0, float4 u1) {
    bf16x8 r;
    r[0] = (short)f2bf(u0.x); r[1] = (short)f2bf(u0.y);
    r[2] = (short)f2bf(u0.z); r[3] = (short)f2bf(u0.w);
    r[4] = (short)f2bf(u1.x); r[5] = (short)f2bf(u1.y);
    r[6] = (short)f2bf(u1.z); r[7] = (short)f2bf(u1.w);
    return r;
}

__global__ void k_zero_int(int* __restrict__ p, int n) {
    int i = blockIdx.x * blockDim.x + threadIdx.x;
    if (i < n) p[i] = 0;
}

// ---------------- Pass A: bucket edges by dst>>8; 32-bit packed (r<<8 | c&255) ----------
__global__ __launch_bounds__(256) void k_passA(const int* __restrict__ row,
                                               const int* __restrict__ col,
                                               int* __restrict__ gcnt,
                                               unsigned* __restrict__ packed,
                                               int E, int NB) {
    __shared__ int lcnt[NBMAX];
    __shared__ int lbase[NBMAX];
    __shared__ int lcur[NBMAX];
    __shared__ int gbaseS[NBMAX];
    __shared__ unsigned stage[4096];
    __shared__ unsigned short stageb[4096];
    __shared__ int s[256];

    int tid = threadIdx.x;
    int t0 = blockIdx.x * 4096;
    int total = min(4096, E - t0);

    for (int b = tid; b < NBMAX; b += 256) { lcnt[b] = 0; lcur[b] = 0; }
    __syncthreads();

    int er[16], ec[16];
#pragma unroll
    for (int j = 0; j < 16; ++j) {
        int e = t0 + j * 256 + tid;
        if (e < E) {
            er[j] = row[e];
            ec[j] = col[e];
            atomicAdd(&lcnt[ec[j] >> 8], 1);
        }
    }
    __syncthreads();

    int c0 = lcnt[2 * tid], c1 = lcnt[2 * tid + 1];
    int p = c0 + c1;
    s[tid] = p;
    __syncthreads();
    for (int off = 1; off < 256; off <<= 1) {
        int t = (tid >= off) ? s[tid - off] : 0;
        __syncthreads();
        s[tid] += t;
        __syncthreads();
    }
    int ebase = s[tid] - p;
    lbase[2 * tid] = ebase;
    lbase[2 * tid + 1] = ebase + c0;
    __syncthreads();

    for (int b = tid; b < NB; b += 256) {
        int lc = lcnt[b];
        if (lc > 0) gbaseS[b] = atomicAdd(&gcnt[b], lc);
    }
    __syncthreads();

#pragma unroll
    for (int j = 0; j < 16; ++j) {
        int e = t0 + j * 256 + tid;
        if (e < E) {
            int b = ec[j] >> 8;
            int pos = lbase[b] + atomicAdd(&lcur[b], 1);
            stage[pos] = ((unsigned)er[j] << 8) | ((unsigned)ec[j] & 255u);
            stageb[pos] = (unsigned short)b;
        }
    }
    __syncthreads();

    for (int j = tid; j < total; j += 256) {
        int b = stageb[j];
        packed[(size_t)b * CAPB + gbaseS[b] + (j - lbase[b])] = stage[j];
    }
}

__global__ void k_bscan(const int* __restrict__ gcnt, int* __restrict__ gbase,
                        int* __restrict__ indptr, int n, int E, int NB) {
    __shared__ int s[512];
    int tid = threadIdx.x;
    int v = (tid < NB) ? gcnt[tid] : 0;
    s[tid] = v;
    __syncthreads();
    for (int off = 1; off < 512; off <<= 1) {
        int t = (tid >= off) ? s[tid - off] : 0;
        __syncthreads();
        s[tid] += t;
        __syncthreads();
    }
    if (tid < NB) gbase[tid] = s[tid] - v;
    if (tid == 0) indptr[n] = E;
}

// ---------------- Pass B: per-bucket CSR finalize ----------------
__global__ __launch_bounds__(256) void k_passB(const unsigned* __restrict__ packed,
                                               const int* __restrict__ gcnt,
                                               const int* __restrict__ gbase,
                                               int* __restrict__ indptr,
                                               float* __restrict__ dinv,
                                               int* __restrict__ srcidx, int n) {
    __shared__ int ncnt[256];
    __shared__ int nbase[256];
    __shared__ int srow[CAPB];

    int b = blockIdx.x;
    int tid = threadIdx.x;
    int nodeBase = b << 8;
    int cntE = min(gcnt[b], CAPB);
    int base = gbase[b];
    size_t pb = (size_t)b * CAPB;

    ncnt[tid] = 0;
    __syncthreads();

    for (int j = tid; j < cntE; j += 256) {
        unsigned e = packed[pb + j];
        atomicAdd(&ncnt[e & 255u], 1);
    }
    __syncthreads();

    int v = ncnt[tid];
    nbase[tid] = v;
    __syncthreads();
    for (int off = 1; off < 256; off <<= 1) {
        int t = (tid >= off) ? nbase[tid - off] : 0;
        __syncthreads();
        nbase[tid] += t;
        __syncthreads();
    }
    int excl = nbase[tid] - v;
    __syncthreads();
    nbase[tid] = excl;

    int node = nodeBase + tid;
    if (node < n) {
        indptr[node] = base + excl;
        dinv[node] = rsqrtf((float)(v + 1));
    }
    ncnt[tid] = 0;
    __syncthreads();

    for (int j = tid; j < cntE; j += 256) {
        unsigned e = packed[pb + j];
        int c = (int)(e & 255u);
        int r = (int)(e >> 8);
        int p = nbase[c] + atomicAdd(&ncnt[c], 1);
        srow[p] = r;
    }
    __syncthreads();

    for (int j = tid; j < cntE; j += 256) srcidx[base + j] = srow[j];
}

// ---------------- weight prep: Wt1 standard; Wt2 with k-permutation pi(p)=(p&7)*16+(p>>3) ----
__global__ void k_wprep(const float* __restrict__ W1, const float* __restrict__ W2,
                        unsigned short* __restrict__ Wt1, unsigned short* __restrict__ Wt2p) {
    int idx = blockIdx.x * blockDim.x + threadIdx.x;
    if (idx < 128 * 128) {
        int colc = idx >> 7, k = idx & 127;
        Wt1[colc * 128 + k] = f2bf(W1[k * 128 + colc]);
    } else if (idx < 128 * 128 + 64 * 128) {
        int j = idx - 128 * 128;
        int colc = j >> 7, p = j & 127;
        int korig = (p & 7) * 16 + (p >> 3);   // pi(p): matches D1q/H1p byte layout
        Wt2p[colc * 128 + p] = f2bf(W2[korig * 64 + colc]);
    }
}

// ---------------- gemm1 (fused concat+cast): D1q = int8(dinv ⊙ (concat(x,cemb) @ W1t^T)) ----
// Output stored column-PERMUTED: byte p = lr*8+cf holds orig col cf*16+lr. Per-row scale.
__global__ __launch_bounds__(256) void k_gemm1(const float* __restrict__ x,
                                               const int* __restrict__ cid,
                                               const float* __restrict__ cemb,
                                               const unsigned short* __restrict__ Wt,
                                               const float* __restrict__ dinv,
                                               unsigned char* __restrict__ D1q,
                                               float* __restrict__ scales, int n) {
    int tid = threadIdx.x;
    int wid = tid >> 6, lane = tid & 63;
    int rbase = blockIdx.x * 64 + wid * 16;
    int lr = lane & 15, kq = lane >> 4;

    int arow = rbase + lr;
    if (arow > n - 1) arow = n - 1;
    const float* xp = x + (size_t)arow * 120 + kq * 8;

    bf16x8 a0 = cvt8(*(const float4*)(xp),      *(const float4*)(xp + 4));
    bf16x8 a1 = cvt8(*(const float4*)(xp + 32), *(const float4*)(xp + 36));
    bf16x8 a2 = cvt8(*(const float4*)(xp + 64), *(const float4*)(xp + 68));
    bf16x8 a3;
    if (kq < 3) {
        a3 = cvt8(*(const float4*)(xp + 96), *(const float4*)(xp + 100));
    } else {
        const float* cp = cemb + (size_t)cid[arow] * 8;
        a3 = cvt8(*(const float4*)(cp), *(const float4*)(cp + 4));
    }

    f32x4 acc[8];
#pragma unroll
    for (int cf = 0; cf < 8; ++cf) acc[cf] = (f32x4){0.f, 0.f, 0.f, 0.f};

#pragma unroll
    for (int cf = 0; cf < 8; ++cf) {
        const unsigned short* bp = Wt + (size_t)(cf * 16 + lr) * 128 + kq * 8;
        bf16x8 b0 = *(const bf16x8*)(bp);
        bf16x8 b1 = *(const bf16x8*)(bp + 32);
        bf16x8 b2 = *(const bf16x8*)(bp + 64);
        bf16x8 b3 = *(const bf16x8*)(bp + 96);
        acc[cf] = __builtin_amdgcn_mfma_f32_16x16x32_bf16(a0, b0, acc[cf], 0, 0, 0);
        acc[cf] = __builtin_amdgcn_mfma_f32_16x16x32_bf16(a1, b1, acc[cf], 0, 0, 0);
        acc[cf] = __builtin_amdgcn_mfma_f32_16x16x32_bf16(a2, b2, acc[cf], 0, 0, 0);
        acc[cf] = __builtin_amdgcn_mfma_f32_16x16x32_bf16(a3, b3, acc[cf], 0, 0, 0);
    }

#pragma unroll
    for (int r = 0; r < 4; ++r) {
        int grow = rbase + kq * 4 + r;
        float dv = (grow < n) ? dinv[grow] : 0.f;
        float m = 0.f;
#pragma unroll
        for (int cf = 0; cf < 8; ++cf) m = fmaxf(m, fabsf(acc[cf][r] * dv));
        // row max across the 16 lanes of this kq group
        m = fmaxf(m, __shfl_xor(m, 1));
        m = fmaxf(m, __shfl_xor(m, 2));
        m = fmaxf(m, __shfl_xor(m, 4));
        m = fmaxf(m, __shfl_xor(m, 8));
        float sinv = (m > 1e-20f) ? 127.f / m : 0.f;
        if (grow < n) {
            if (lr == 0) scales[grow] = m * (1.f / 127.f);
            unsigned lo = 0, hi = 0;
#pragma unroll
            for (int cf = 0; cf < 4; ++cf) {
                int q8 = (int)rintf(acc[cf][r] * dv * sinv);
                lo |= ((unsigned)(q8 & 255)) << (8 * cf);
            }
#pragma unroll
            for (int cf = 4; cf < 8; ++cf) {
                int q8 = (int)rintf(acc[cf][r] * dv * sinv);
                hi |= ((unsigned)(q8 & 255)) << (8 * (cf - 4));
            }
            *(uint2*)&D1q[(size_t)grow * 128 + lr * 8] = make_uint2(lo, hi);
        }
    }
}

// ---------------- gemm2: D2 = dinv ⊙ (H1p[N,128] @ Wt2p^T), standard bf16 out ------------
template <int NOUT>
__global__ __launch_bounds__(256) void k_gemm_bf16(const unsigned short* __restrict__ A,
                                                   const unsigned short* __restrict__ Wt,
                                                   const float* __restrict__ dinv,
                                                   unsigned short* __restrict__ D, int n) {
    constexpr int NCF = NOUT / 16;
    int tid = threadIdx.x;
    int wid = tid >> 6, lane = tid & 63;
    int rbase = blockIdx.x * 64 + wid * 16;
    int lr = lane & 15, kq = lane >> 4;

    int arow = rbase + lr;
    if (arow > n - 1) arow = n - 1;
    const unsigned short* ap = A + (size_t)arow * 128 + kq * 8;
    bf16x8 a0 = *(const bf16x8*)(ap);
    bf16x8 a1 = *(const bf16x8*)(ap + 32);
    bf16x8 a2 = *(const bf16x8*)(ap + 64);
    bf16x8 a3 = *(const bf16x8*)(ap + 96);

    f32x4 acc[NCF];
#pragma unroll
    for (int cf = 0; cf < NCF; ++cf) acc[cf] = (f32x4){0.f, 0.f, 0.f, 0.f};

#pragma unroll
    for (int cf = 0; cf < NCF; ++cf) {
        const unsigned short* bp = Wt + (size_t)(cf * 16 + lr) * 128 + kq * 8;
        bf16x8 b0 = *(const bf16x8*)(bp);
        bf16x8 b1 = *(const bf16x8*)(bp + 32);
        bf16x8 b2 = *(const bf16x8*)(bp + 64);
        bf16x8 b3 = *(const bf16x8*)(bp + 96);
        acc[cf] = __builtin_amdgcn_mfma_f32_16x16x32_bf16(a0, b0, acc[cf], 0, 0, 0);
        acc[cf] = __builtin_amdgcn_mfma_f32_16x16x32_bf16(a1, b1, acc[cf], 0, 0, 0);
        acc[cf] = __builtin_amdgcn_mfma_f32_16x16x32_bf16(a2, b2, acc[cf], 0, 0, 0);
        acc[cf] = __builtin_amdgcn_mfma_f32_16x16x32_bf16(a3, b3, acc[cf], 0, 0, 0);
    }

    float dv[4];
#pragma unroll
    for (int r = 0; r < 4; ++r) {
        int grow = rbase + kq * 4 + r;
        dv[r] = (grow < n) ? dinv[grow] : 0.f;
    }
#pragma unroll
    for (int cf = 0; cf < NCF; ++cf) {
#pragma unroll
        for (int r = 0; r < 4; ++r) {
            int grow = rbase + kq * 4 + r;
            if (grow < n) D[(size_t)grow * NOUT + cf * 16 + lr] = f2bf(acc[cf][r] * dv[r]);
        }
    }
}

// ---------------- agg1: int8 gather + per-row scale; writes H1p (permuted cols, bf16) ----
// H1p[i][p] = relu(dinv_i * (sum_e s_src*q[src][p] + s_i*q[i][p]) + b1[pi(p)])
__global__ __launch_bounds__(64) void k_agg1(const unsigned char* __restrict__ Hq,
                                             const float* __restrict__ scales,
                                             const int* __restrict__ indptr,
                                             const int* __restrict__ srcidx,
                                             const float* __restrict__ dinv,
                                             const float* __restrict__ bias,
                                             unsigned* __restrict__ Out, int n) {
    int i = blockIdx.x;
    int lane = threadIdx.x;
    int c0 = ((2 * lane) & 7) * 16 + (lane >> 2);  // orig col of byte p=2*lane; p+1 -> c0+16
    float bx = bias[c0], by = bias[c0 + 16];
    float di = dinv[i];

    unsigned short sq = *(const unsigned short*)(Hq + (size_t)i * 128 + 2 * lane);
    float ss = scales[i];
    float ax = ss * (float)(signed char)(sq & 255);
    float ay = ss * (float)(signed char)(sq >> 8);

    int e0 = indptr[i], e1 = indptr[i + 1];
#pragma unroll 4
    for (int e = e0; e < e1; ++e) {
        int s = srcidx[e];
        unsigned short q = *(const unsigned short*)(Hq + (size_t)s * 128 + 2 * lane);
        float sc = scales[s];
        ax += sc * (float)(signed char)(q & 255);
        ay += sc * (float)(signed char)(q >> 8);
    }
    float ox = fmaxf(di * ax + bx, 0.f);
    float oy = fmaxf(di * ay + by, 0.f);
    Out[(size_t)i * 64 + lane] = packbf(ox, oy);
}

// ---------------- agg2 (round-6 best shape): bf16 gather, f32 out ----------------
__global__ __launch_bounds__(64) void k_agg2(const unsigned* __restrict__ Hs,
                                             const int* __restrict__ indptr,
                                             const int* __restrict__ srcidx,
                                             const float* __restrict__ dinv,
                                             const float* __restrict__ bias,
                                             float2* __restrict__ Out, int n) {
    int i = blockIdx.x;
    int lane = threadIdx.x;
    int v = lane & 31, h = lane >> 5;
    float di = dinv[i];
    float2 b = *(const float2*)&bias[v * 2];
    float ax = 0.f, ay = 0.f;
    if (h == 0) {
        unsigned sv = Hs[(size_t)i * 32 + v];
        ax = bfu_lo(sv);
        ay = bfu_hi(sv);
    }
    int e0 = indptr[i], e1 = indptr[i + 1];
#pragma unroll 4
    for (int e = e0 + h; e < e1; e += 2) {
        unsigned w = Hs[(size_t)srcidx[e] * 32 + v];
        ax += bfu_lo(w);
        ay += bfu_hi(w);
    }
    ax += __shfl_xor(ax, 32);
    ay += __shfl_xor(ay, 32);
    if (h == 0) {
        Out[(size_t)i * 32 + v] = make_float2(di * ax + b.x, di * ay + b.y);
    }
}

// ---------------- launch ----------------

extern "C" void kernel_launch(void* const* d_in, const int* in_sizes, int n_in,
                              void* d_out, int out_size, void* d_ws, size_t ws_size,
                              hipStream_t stream) {
    const float* x    = (const float*)d_in[0];
    const int*   eidx = (const int*)d_in[1];
    const int*   cid  = (const int*)d_in[2];
    const float* cemb = (const float*)d_in[3];
    const float* W1   = (const float*)d_in[4];
    const float* b1   = (const float*)d_in[5];
    const float* W2   = (const float*)d_in[6];
    const float* b2   = (const float*)d_in[7];
    float* out = (float*)d_out;

    int n = in_sizes[2];
    int E = in_sizes[1] / 2;
    const int* row = eidx;
    const int* col = eidx + E;
    int NB = (n + 255) / 256;

    char* ws = (char*)d_ws;
    auto alloc = [&](size_t bytes) {
        char* p = ws;
        ws += (bytes + 255) & ~(size_t)255;
        return p;
    };
    float*          dinv   = (float*)alloc((size_t)n * 4);
    int*            gcnt   = (int*)alloc((size_t)NB * 4);
    int*            gbase  = (int*)alloc((size_t)NB * 4);
    int*            indptr = (int*)alloc((size_t)(n + 1) * 4);
    int*            srcidx = (int*)alloc((size_t)E * 4);
    unsigned*       packed = (unsigned*)alloc((size_t)NB * CAPB * 4);
    unsigned short* Wt1    = (unsigned short*)alloc(128 * 128 * 2);
    unsigned short* Wt2p   = (unsigned short*)alloc(64 * 128 * 2);
    unsigned char*  D1q    = (unsigned char*)alloc((size_t)n * 128);
    float*          scales = (float*)alloc((size_t)n * 4);
    unsigned short* H1p    = (unsigned short*)alloc((size_t)n * 128 * 2);
    unsigned short* D2     = (unsigned short*)alloc((size_t)n * 64 * 2);

    // CSR build (bucketed two-pass, packed32)
    k_zero_int<<<(NB + 255) / 256, 256, 0, stream>>>(gcnt, NB);
    k_passA<<<(E + 4095) / 4096, 256, 0, stream>>>(row, col, gcnt, packed, E, NB);
    k_bscan<<<1, 512, 0, stream>>>(gcnt, gbase, indptr, n, E, NB);
    k_passB<<<NB, 256, 0, stream>>>(packed, gcnt, gbase, indptr, dinv, srcidx, n);

    // weight prep
    k_wprep<<<(128 * 128 + 64 * 128 + 255) / 256, 256, 0, stream>>>(W1, W2, Wt1, Wt2p);

    int gb = (n + 63) / 64;
    // layer 1
    k_gemm1<<<gb, 256, 0, stream>>>(x, cid, cemb, Wt1, dinv, D1q, scales, n);
    k_agg1<<<n, 64, 0, stream>>>(D1q, scales, indptr, srcidx, dinv, b1,
                                 (unsigned*)H1p, n);
    // layer 2
    k_gemm_bf16<64><<<gb, 256, 0, stream>>>(H1p, Wt2p, dinv, D2, n);
    k_agg2<<<n, 64, 0, stream>>>((const unsigned*)D2, indptr, srcidx, dinv, b2,
                                 (float2*)out, n);
}

// Round 10
// 195.171 us; speedup vs baseline: 1.2578x; 1.0926x over previous
//
#include <hip/hip_runtime.h>

typedef __attribute__((ext_vector_type(8))) short bf16x8;
typedef __attribute__((ext_vector_type(4))) float f32x4;

#define CAPB 5632   // per-bucket capacity (mean E/NB ~= 4092, sd ~64)
#define NBMAX 512   // supports n <= 131072

static __device__ __forceinline__ unsigned short f2bf(float f) {
    unsigned u = __float_as_uint(f);
    unsigned r = (u + 0x7fff + ((u >> 16) & 1)) >> 16;  // RNE
    return (unsigned short)r;
}
static __device__ __forceinline__ float bfu_lo(unsigned v) { return __uint_as_float(v << 16); }
static __device__ __forceinline__ float bfu_hi(unsigned v) { return __uint_as_float(v & 0xffff0000u); }
static __device__ __forceinline__ unsigned packbf(float a, float b) {
    return (unsigned)f2bf(a) | ((unsigned)f2bf(b) << 16);
}

static __device__ __forceinline__ bf16x8 cvt8(float4 u0, float4 u1) {
    bf16x8 r;
    r[0] = (short)f2bf(u0.x); r[1] = (short)f2bf(u0.y);
    r[2] = (short)f2bf(u0.z); r[3] = (short)f2bf(u0.w);
    r[4] = (short)f2bf(u1.x); r[5] = (short)f2bf(u1.y);
    r[6] = (short)f2bf(u1.z); r[7] = (short)f2bf(u1.w);
    return r;
}

__global__ void k_zero_int(int* __restrict__ p, int n) {
    int i = blockIdx.x * blockDim.x + threadIdx.x;
    if (i < n) p[i] = 0;
}

// ---------------- Pass A: bucket edges by dst>>8; 32-bit packed (r<<8 | c&255) ----------
__global__ __launch_bounds__(256) void k_passA(const int* __restrict__ row,
                                               const int* __restrict__ col,
                                               int* __restrict__ gcnt,
                                               unsigned* __restrict__ packed,
                                               int E, int NB) {
    __shared__ int lcnt[NBMAX];
    __shared__ int lbase[NBMAX];
    __shared__ int lcur[NBMAX];
    __shared__ int gbaseS[NBMAX];
    __shared__ unsigned stage[4096];
    __shared__ unsigned short stageb[4096];
    __shared__ int s[256];

    int tid = threadIdx.x;
    int t0 = blockIdx.x * 4096;
    int total = min(4096, E - t0);

    for (int b = tid; b < NBMAX; b += 256) { lcnt[b] = 0; lcur[b] = 0; }
    __syncthreads();

    int er[16], ec[16];
#pragma unroll
    for (int j = 0; j < 16; ++j) {
        int e = t0 + j * 256 + tid;
        if (e < E) {
            er[j] = row[e];
            ec[j] = col[e];
            atomicAdd(&lcnt[ec[j] >> 8], 1);
        }
    }
    __syncthreads();

    int c0 = lcnt[2 * tid], c1 = lcnt[2 * tid + 1];
    int p = c0 + c1;
    s[tid] = p;
    __syncthreads();
    for (int off = 1; off < 256; off <<= 1) {
        int t = (tid >= off) ? s[tid - off] : 0;
        __syncthreads();
        s[tid] += t;
        __syncthreads();
    }
    int ebase = s[tid] - p;
    lbase[2 * tid] = ebase;
    lbase[2 * tid + 1] = ebase + c0;
    __syncthreads();

    for (int b = tid; b < NB; b += 256) {
        int lc = lcnt[b];
        if (lc > 0) gbaseS[b] = atomicAdd(&gcnt[b], lc);
    }
    __syncthreads();

#pragma unroll
    for (int j = 0; j < 16; ++j) {
        int e = t0 + j * 256 + tid;
        if (e < E) {
            int b = ec[j] >> 8;
            int pos = lbase[b] + atomicAdd(&lcur[b], 1);
            stage[pos] = ((unsigned)er[j] << 8) | ((unsigned)ec[j] & 255u);
            stageb[pos] = (unsigned short)b;
        }
    }
    __syncthreads();

    for (int j = tid; j < total; j += 256) {
        int b = stageb[j];
        packed[(size_t)b * CAPB + gbaseS[b] + (j - lbase[b])] = stage[j];
    }
}

__global__ void k_bscan(const int* __restrict__ gcnt, int* __restrict__ gbase,
                        int* __restrict__ indptr, int n, int E, int NB) {
    __shared__ int s[512];
    int tid = threadIdx.x;
    int v = (tid < NB) ? gcnt[tid] : 0;
    s[tid] = v;
    __syncthreads();
    for (int off = 1; off < 512; off <<= 1) {
        int t = (tid >= off) ? s[tid - off] : 0;
        __syncthreads();
        s[tid] += t;
        __syncthreads();
    }
    if (tid < NB) gbase[tid] = s[tid] - v;
    if (tid == 0) indptr[n] = E;
}

// ---------------- Pass B: per-bucket CSR finalize ----------------
__global__ __launch_bounds__(256) void k_passB(const unsigned* __restrict__ packed,
                                               const int* __restrict__ gcnt,
                                               const int* __restrict__ gbase,
                                               int* __restrict__ indptr,
                                               float* __restrict__ dinv,
                                               int* __restrict__ srcidx, int n) {
    __shared__ int ncnt[256];
    __shared__ int nbase[256];
    __shared__ int srow[CAPB];

    int b = blockIdx.x;
    int tid = threadIdx.x;
    int nodeBase = b << 8;
    int cntE = min(gcnt[b], CAPB);
    int base = gbase[b];
    size_t pb = (size_t)b * CAPB;

    ncnt[tid] = 0;
    __syncthreads();

    for (int j = tid; j < cntE; j += 256) {
        unsigned e = packed[pb + j];
        atomicAdd(&ncnt[e & 255u], 1);
    }
    __syncthreads();

    int v = ncnt[tid];
    nbase[tid] = v;
    __syncthreads();
    for (int off = 1; off < 256; off <<= 1) {
        int t = (tid >= off) ? nbase[tid - off] : 0;
        __syncthreads();
        nbase[tid] += t;
        __syncthreads();
    }
    int excl = nbase[tid] - v;
    __syncthreads();
    nbase[tid] = excl;

    int node = nodeBase + tid;
    if (node < n) {
        indptr[node] = base + excl;
        dinv[node] = rsqrtf((float)(v + 1));
    }
    ncnt[tid] = 0;
    __syncthreads();

    for (int j = tid; j < cntE; j += 256) {
        unsigned e = packed[pb + j];
        int c = (int)(e & 255u);
        int r = (int)(e >> 8);
        int p = nbase[c] + atomicAdd(&ncnt[c], 1);
        srow[p] = r;
    }
    __syncthreads();

    for (int j = tid; j < cntE; j += 256) srcidx[base + j] = srow[j];
}

// ---------------- weight prep: Wt1; Wt2 k-permuted; b1 permuted (pi(p)=(p&7)*16+(p>>3)) ----
__global__ void k_wprep(const float* __restrict__ W1, const float* __restrict__ W2,
                        const float* __restrict__ b1,
                        unsigned short* __restrict__ Wt1, unsigned short* __restrict__ Wt2p,
                        float* __restrict__ b1p) {
    int idx = blockIdx.x * blockDim.x + threadIdx.x;
    if (idx < 128 * 128) {
        int colc = idx >> 7, k = idx & 127;
        Wt1[colc * 128 + k] = f2bf(W1[k * 128 + colc]);
    } else if (idx < 128 * 128 + 64 * 128) {
        int j = idx - 128 * 128;
        int colc = j >> 7, p = j & 127;
        int korig = (p & 7) * 16 + (p >> 3);   // pi(p): matches D1q/H1p byte layout
        Wt2p[colc * 128 + p] = f2bf(W2[korig * 64 + colc]);
    } else if (idx < 128 * 128 + 64 * 128 + 128) {
        int p = idx - (128 * 128 + 64 * 128);
        b1p[p] = b1[(p & 7) * 16 + (p >> 3)];
    }
}

// ---------------- gemm1 (fused concat+cast): D1q = int8(dinv ⊙ (concat(x,cemb) @ W1t^T)) ----
// Output stored column-PERMUTED: byte p = lr*8+cf holds orig col cf*16+lr. Per-row scale.
__global__ __launch_bounds__(256) void k_gemm1(const float* __restrict__ x,
                                               const int* __restrict__ cid,
                                               const float* __restrict__ cemb,
                                               const unsigned short* __restrict__ Wt,
                                               const float* __restrict__ dinv,
                                               unsigned char* __restrict__ D1q,
                                               float* __restrict__ scales, int n) {
    int tid = threadIdx.x;
    int wid = tid >> 6, lane = tid & 63;
    int rbase = blockIdx.x * 64 + wid * 16;
    int lr = lane & 15, kq = lane >> 4;

    int arow = rbase + lr;
    if (arow > n - 1) arow = n - 1;
    const float* xp = x + (size_t)arow * 120 + kq * 8;

    bf16x8 a0 = cvt8(*(const float4*)(xp),      *(const float4*)(xp + 4));
    bf16x8 a1 = cvt8(*(const float4*)(xp + 32), *(const float4*)(xp + 36));
    bf16x8 a2 = cvt8(*(const float4*)(xp + 64), *(const float4*)(xp + 68));
    bf16x8 a3;
    if (kq < 3) {
        a3 = cvt8(*(const float4*)(xp + 96), *(const float4*)(xp + 100));
    } else {
        const float* cp = cemb + (size_t)cid[arow] * 8;
        a3 = cvt8(*(const float4*)(cp), *(const float4*)(cp + 4));
    }

    f32x4 acc[8];
#pragma unroll
    for (int cf = 0; cf < 8; ++cf) acc[cf] = (f32x4){0.f, 0.f, 0.f, 0.f};

#pragma unroll
    for (int cf = 0; cf < 8; ++cf) {
        const unsigned short* bp = Wt + (size_t)(cf * 16 + lr) * 128 + kq * 8;
        bf16x8 b0 = *(const bf16x8*)(bp);
        bf16x8 b1 = *(const bf16x8*)(bp + 32);
        bf16x8 b2 = *(const bf16x8*)(bp + 64);
        bf16x8 b3 = *(const bf16x8*)(bp + 96);
        acc[cf] = __builtin_amdgcn_mfma_f32_16x16x32_bf16(a0, b0, acc[cf], 0, 0, 0);
        acc[cf] = __builtin_amdgcn_mfma_f32_16x16x32_bf16(a1, b1, acc[cf], 0, 0, 0);
        acc[cf] = __builtin_amdgcn_mfma_f32_16x16x32_bf16(a2, b2, acc[cf], 0, 0, 0);
        acc[cf] = __builtin_amdgcn_mfma_f32_16x16x32_bf16(a3, b3, acc[cf], 0, 0, 0);
    }

#pragma unroll
    for (int r = 0; r < 4; ++r) {
        int grow = rbase + kq * 4 + r;
        float dv = (grow < n) ? dinv[grow] : 0.f;
        float m = 0.f;
#pragma unroll
        for (int cf = 0; cf < 8; ++cf) m = fmaxf(m, fabsf(acc[cf][r] * dv));
        m = fmaxf(m, __shfl_xor(m, 1));
        m = fmaxf(m, __shfl_xor(m, 2));
        m = fmaxf(m, __shfl_xor(m, 4));
        m = fmaxf(m, __shfl_xor(m, 8));
        float sinv = (m > 1e-20f) ? 127.f / m : 0.f;
        if (grow < n) {
            if (lr == 0) scales[grow] = m * (1.f / 127.f);
            unsigned lo = 0, hi = 0;
#pragma unroll
            for (int cf = 0; cf < 4; ++cf) {
                int q8 = (int)rintf(acc[cf][r] * dv * sinv);
                lo |= ((unsigned)(q8 & 255)) << (8 * cf);
            }
#pragma unroll
            for (int cf = 4; cf < 8; ++cf) {
                int q8 = (int)rintf(acc[cf][r] * dv * sinv);
                hi |= ((unsigned)(q8 & 255)) << (8 * (cf - 4));
            }
            *(uint2*)&D1q[(size_t)grow * 128 + lr * 8] = make_uint2(lo, hi);
        }
    }
}

// ---------------- gemm2: D2 = dinv ⊙ (H1p[N,128] @ Wt2p^T), standard bf16 out ------------
template <int NOUT>
__global__ __launch_bounds__(256) void k_gemm_bf16(const unsigned short* __restrict__ A,
                                                   const unsigned short* __restrict__ Wt,
                                                   const float* __restrict__ dinv,
                                                   unsigned short* __restrict__ D, int n) {
    constexpr int NCF = NOUT / 16;
    int tid = threadIdx.x;
    int wid = tid >> 6, lane = tid & 63;
    int rbase = blockIdx.x * 64 + wid * 16;
    int lr = lane & 15, kq = lane >> 4;

    int arow = rbase + lr;
    if (arow > n - 1) arow = n - 1;
    const unsigned short* ap = A + (size_t)arow * 128 + kq * 8;
    bf16x8 a0 = *(const bf16x8*)(ap);
    bf16x8 a1 = *(const bf16x8*)(ap + 32);
    bf16x8 a2 = *(const bf16x8*)(ap + 64);
    bf16x8 a3 = *(const bf16x8*)(ap + 96);

    f32x4 acc[NCF];
#pragma unroll
    for (int cf = 0; cf < NCF; ++cf) acc[cf] = (f32x4){0.f, 0.f, 0.f, 0.f};

#pragma unroll
    for (int cf = 0; cf < NCF; ++cf) {
        const unsigned short* bp = Wt + (size_t)(cf * 16 + lr) * 128 + kq * 8;
        bf16x8 b0 = *(const bf16x8*)(bp);
        bf16x8 b1 = *(const bf16x8*)(bp + 32);
        bf16x8 b2 = *(const bf16x8*)(bp + 64);
        bf16x8 b3 = *(const bf16x8*)(bp + 96);
        acc[cf] = __builtin_amdgcn_mfma_f32_16x16x32_bf16(a0, b0, acc[cf], 0, 0, 0);
        acc[cf] = __builtin_amdgcn_mfma_f32_16x16x32_bf16(a1, b1, acc[cf], 0, 0, 0);
        acc[cf] = __builtin_amdgcn_mfma_f32_16x16x32_bf16(a2, b2, acc[cf], 0, 0, 0);
        acc[cf] = __builtin_amdgcn_mfma_f32_16x16x32_bf16(a3, b3, acc[cf], 0, 0, 0);
    }

    float dv[4];
#pragma unroll
    for (int r = 0; r < 4; ++r) {
        int grow = rbase + kq * 4 + r;
        dv[r] = (grow < n) ? dinv[grow] : 0.f;
    }
#pragma unroll
    for (int cf = 0; cf < NCF; ++cf) {
#pragma unroll
        for (int r = 0; r < 4; ++r) {
            int grow = rbase + kq * 4 + r;
            if (grow < n) D[(size_t)grow * NOUT + cf * 16 + lr] = f2bf(acc[cf][r] * dv[r]);
        }
    }
}

// ---------------- agg1: 4 nodes/wave (16 lanes each), int8 rows + per-row scale ----------
// lane group g owns node i=blk*4+g; lane gl covers bytes p=gl*8..gl*8+7 (orig col j*16+gl).
// H1p[i][p] = relu(dinv_i*(sum_e s_src*q[src][p] + s_i*q[i][p]) + b1p[p])
__global__ __launch_bounds__(64) void k_agg1(const uint2* __restrict__ rows,   // D1q as [n][16] uint2
                                             const float* __restrict__ scales,
                                             const int* __restrict__ indptr,
                                             const int* __restrict__ srcidx,
                                             const float* __restrict__ dinv,
                                             const float* __restrict__ b1p,
                                             uint4* __restrict__ Out, int n) {
    int lane = threadIdx.x;
    int g = lane >> 4, gl = lane & 15;
    int i = blockIdx.x * 4 + g;
    if (i > n - 1) i = n - 1;

    float di = dinv[i];
    float4 bA = *(const float4*)&b1p[gl * 8];
    float4 bB = *(const float4*)&b1p[gl * 8 + 4];

    uint2 sq = rows[(size_t)i * 16 + gl];
    float ss = scales[i];
    float a[8];
#pragma unroll
    for (int j = 0; j < 4; ++j) {
        a[j]     = ss * (float)(signed char)((sq.x >> (8 * j)) & 255u);
        a[j + 4] = ss * (float)(signed char)((sq.y >> (8 * j)) & 255u);
    }

    int e0 = indptr[i];
    int d = indptr[i + 1] - e0;
    int m = max(d, __shfl_xor(d, 16));
    m = max(m, __shfl_xor(m, 32));

#pragma unroll 4
    for (int t = 0; t < m; ++t) {
        bool act = t < d;
        int s = act ? srcidx[e0 + t] : i;
        float sc = act ? scales[s] : 0.f;
        uint2 q = rows[(size_t)s * 16 + gl];
#pragma unroll
        for (int j = 0; j < 4; ++j) {
            a[j]     += sc * (float)(signed char)((q.x >> (8 * j)) & 255u);
            a[j + 4] += sc * (float)(signed char)((q.y >> (8 * j)) & 255u);
        }
    }

    uint4 o;
    o.x = packbf(fmaxf(di * a[0] + bA.x, 0.f), fmaxf(di * a[1] + bA.y, 0.f));
    o.y = packbf(fmaxf(di * a[2] + bA.z, 0.f), fmaxf(di * a[3] + bA.w, 0.f));
    o.z = packbf(fmaxf(di * a[4] + bB.x, 0.f), fmaxf(di * a[5] + bB.y, 0.f));
    o.w = packbf(fmaxf(di * a[6] + bB.z, 0.f), fmaxf(di * a[7] + bB.w, 0.f));
    Out[(size_t)i * 16 + gl] = o;
}

// ---------------- agg2: 4 nodes/wave, bf16 rows (64 cols = 128B), f32 out ----------------
__global__ __launch_bounds__(64) void k_agg2(const uint2* __restrict__ Hs,   // D2 as [n][16] uint2
                                             const int* __restrict__ indptr,
                                             const int* __restrict__ srcidx,
                                             const float* __restrict__ dinv,
                                             const float* __restrict__ bias,
                                             float4* __restrict__ Out, int n) {
    int lane = threadIdx.x;
    int g = lane >> 4, gl = lane & 15;
    int i = blockIdx.x * 4 + g;
    if (i > n - 1) i = n - 1;

    float di = dinv[i];
    float4 b = *(const float4*)&bias[gl * 4];

    uint2 sv = Hs[(size_t)i * 16 + gl];
    float a0 = bfu_lo(sv.x), a1 = bfu_hi(sv.x);
    float a2 = bfu_lo(sv.y), a3 = bfu_hi(sv.y);

    int e0 = indptr[i];
    int d = indptr[i + 1] - e0;
    int m = max(d, __shfl_xor(d, 16));
    m = max(m, __shfl_xor(m, 32));

#pragma unroll 4
    for (int t = 0; t < m; ++t) {
        bool act = t < d;
        int s = act ? srcidx[e0 + t] : i;
        float msk = act ? 1.f : 0.f;
        uint2 w = Hs[(size_t)s * 16 + gl];
        a0 += msk * bfu_lo(w.x);
        a1 += msk * bfu_hi(w.x);
        a2 += msk * bfu_lo(w.y);
        a3 += msk * bfu_hi(w.y);
    }
    Out[(size_t)i * 16 + gl] = make_float4(di * a0 + b.x, di * a1 + b.y,
                                           di * a2 + b.z, di * a3 + b.w);
}

// ---------------- launch ----------------

extern "C" void kernel_launch(void* const* d_in, const int* in_sizes, int n_in,
                              void* d_out, int out_size, void* d_ws, size_t ws_size,
                              hipStream_t stream) {
    const float* x    = (const float*)d_in[0];
    const int*   eidx = (const int*)d_in[1];
    const int*   cid  = (const int*)d_in[2];
    const float* cemb = (const float*)d_in[3];
    const float* W1   = (const float*)d_in[4];
    const float* b1   = (const float*)d_in[5];
    const float* W2   = (const float*)d_in[6];
    const float* b2   = (const float*)d_in[7];
    float* out = (float*)d_out;

    int n = in_sizes[2];
    int E = in_sizes[1] / 2;
    const int* row = eidx;
    const int* col = eidx + E;
    int NB = (n + 255) / 256;

    char* ws = (char*)d_ws;
    auto alloc = [&](size_t bytes) {
        char* p = ws;
        ws += (bytes + 255) & ~(size_t)255;
        return p;
    };
    float*          dinv   = (float*)alloc((size_t)n * 4);
    int*            gcnt   = (int*)alloc((size_t)NB * 4);
    int*            gbase  = (int*)alloc((size_t)NB * 4);
    int*            indptr = (int*)alloc((size_t)(n + 1) * 4);
    int*            srcidx = (int*)alloc((size_t)E * 4);
    unsigned*       packed = (unsigned*)alloc((size_t)NB * CAPB * 4);
    unsigned short* Wt1    = (unsigned short*)alloc(128 * 128 * 2);
    unsigned short* Wt2p   = (unsigned short*)alloc(64 * 128 * 2);
    float*          b1p    = (float*)alloc(128 * 4);
    unsigned char*  D1q    = (unsigned char*)alloc((size_t)n * 128);
    float*          scales = (float*)alloc((size_t)n * 4);
    unsigned short* H1p    = (unsigned short*)alloc((size_t)n * 128 * 2);
    unsigned short* D2     = (unsigned short*)alloc((size_t)n * 64 * 2);

    // CSR build (bucketed two-pass, packed32)
    k_zero_int<<<(NB + 255) / 256, 256, 0, stream>>>(gcnt, NB);
    k_passA<<<(E + 4095) / 4096, 256, 0, stream>>>(row, col, gcnt, packed, E, NB);
    k_bscan<<<1, 512, 0, stream>>>(gcnt, gbase, indptr, n, E, NB);
    k_passB<<<NB, 256, 0, stream>>>(packed, gcnt, gbase, indptr, dinv, srcidx, n);

    // weight prep
    k_wprep<<<(128 * 128 + 64 * 128 + 128 + 255) / 256, 256, 0, stream>>>(W1, W2, b1,
                                                                          Wt1, Wt2p, b1p);

    int gb = (n + 63) / 64;
    int ga = (n + 3) / 4;
    // layer 1
    k_gemm1<<<gb, 256, 0, stream>>>(x, cid, cemb, Wt1, dinv, D1q, scales, n);
    k_agg1<<<ga, 64, 0, stream>>>((const uint2*)D1q, scales, indptr, srcidx, dinv, b1p,
                                  (uint4*)H1p, n);
    // layer 2
    k_gemm_bf16<64><<<gb, 256, 0, stream>>>(H1p, Wt2p, dinv, D2, n);
    k_agg2<<<ga, 64, 0, stream>>>((const uint2*)D2, indptr, srcidx, dinv, b2,
                                  (float4*)out, n);
}